// Round 2
// baseline (387.932 us; speedup 1.0000x reference)
//
#include <hip/hip_runtime.h>
#include <hip/hip_bf16.h>
#include <stdint.h>

typedef __bf16 bf16_t;
typedef __bf16 bf16x8 __attribute__((ext_vector_type(8)));
typedef float f32x4 __attribute__((ext_vector_type(4)));

#define BB 8
#define KK 1024
#define LL 1024
#define DD 1024
#define OO 6
#define EE 128
#define NN 768   // OO*EE

// ---------------------------------------------------------------------------
__device__ __forceinline__ void async_copy16(const void* gptr, void* lds) {
    __builtin_amdgcn_global_load_lds(
        (__attribute__((address_space(1))) void*)gptr,
        (__attribute__((address_space(3))) void*)lds,
        16, 0, 0);
}

__device__ __forceinline__ void split_bf16(float x, bf16_t& hi, bf16_t& lo) {
    hi = (bf16_t)x;
    lo = (bf16_t)(x - (float)hi);   // a-hi exact (Sterbenz); lo rel err ~2^-16
}

// ---------------------------------------------------------------------------
// A (8192,1024) f32 -> Ah, Al bf16 planes (row-major, same shape).
__global__ __launch_bounds__(256) void convert_a(
    const float* __restrict__ A, bf16_t* __restrict__ Ah, bf16_t* __restrict__ Al)
{
    const long i = ((long)blockIdx.x * 256 + threadIdx.x) * 4;
    const float4 x = *(const float4*)(A + i);
    union { bf16_t h[4]; uint2 u; } ph, pl;
    split_bf16(x.x, ph.h[0], pl.h[0]);
    split_bf16(x.y, ph.h[1], pl.h[1]);
    split_bf16(x.z, ph.h[2], pl.h[2]);
    split_bf16(x.w, ph.h[3], pl.h[3]);
    *(uint2*)(Ah + i) = ph.u;
    *(uint2*)(Al + i) = pl.u;
}

// ---------------------------------------------------------------------------
// W (O,D,E) f32 -> Wt_hi, Wt_lo (O,E,D) bf16 (transpose so GEMM-B is d-contig).
__global__ __launch_bounds__(256) void convert_w(
    const float* __restrict__ W, bf16_t* __restrict__ Wth, bf16_t* __restrict__ Wtl)
{
    __shared__ float t[32][33];
    const int o  = blockIdx.z;
    const int d0 = blockIdx.x * 32;
    const int e0 = blockIdx.y * 32;
    const int tx = threadIdx.x & 31;
    const int ty = threadIdx.x >> 5;   // 0..7
    const float* Wo = W + (long)o * DD * EE;
    bf16_t* Ho = Wth + (long)o * EE * DD;
    bf16_t* Lo = Wtl + (long)o * EE * DD;
#pragma unroll
    for (int p = 0; p < 4; ++p)
        t[p * 8 + ty][tx] = Wo[(long)(d0 + p * 8 + ty) * EE + e0 + tx];
    __syncthreads();
#pragma unroll
    for (int p = 0; p < 4; ++p) {
        const float val = t[tx][p * 8 + ty];
        bf16_t h, l;
        split_bf16(val, h, l);
        const long idx = (long)(e0 + p * 8 + ty) * DD + d0 + tx;
        Ho[idx] = h;
        Lo[idx] = l;
    }
}

// ---------------------------------------------------------------------------
// priors GEMM, split precision: C = (Ah+Al)(Bh+Bl)^T ~= AhBh + AlBh + AhBl.
// C(8192,768) f32. 128x128 tile, BK=32, 4 waves, wave = 64x64 via 4x4 mfma.
__global__ __launch_bounds__(256) void gemm_priors(
    const bf16_t* __restrict__ Ah, const bf16_t* __restrict__ Al,
    const bf16_t* __restrict__ Bh, const bf16_t* __restrict__ Bl,
    float* __restrict__ C)
{
    __shared__ alignas(16) bf16_t sAh[128 * 32];
    __shared__ alignas(16) bf16_t sAl[128 * 32];
    __shared__ alignas(16) bf16_t sBh[128 * 32];
    __shared__ alignas(16) bf16_t sBl[128 * 32];

    const int tid  = threadIdx.x;
    const int w    = tid >> 6;
    const int lane = tid & 63;
    const int bm   = blockIdx.x;   // 0..63
    const int bn   = blockIdx.y;   // 0..5
    const int qr   = (w >> 1) * 64;
    const int qc   = (w & 1) * 64;
    const int r16  = lane & 15;
    const int q    = lane >> 4;

    f32x4 acc[4][4] = {};

    // staging map: instr (w,i) covers rows w*32+i*16 .. +15 of the tile;
    // lane -> row (lane>>2), k-elems (lane&3)*8. LDS dest lane-linear.
    const int mrow = w * 32 + (lane >> 2);
    const int kcol = (lane & 3) * 8;

    const long aoff = (long)(bm * 128 + mrow) * DD + kcol;
    const long boff = (long)(bn * 128 + mrow) * DD + kcol;
    const bf16_t* gAh0 = Ah + aoff;  const bf16_t* gAh1 = gAh0 + 16 * DD;
    const bf16_t* gAl0 = Al + aoff;  const bf16_t* gAl1 = gAl0 + 16 * DD;
    const bf16_t* gBh0 = Bh + boff;  const bf16_t* gBh1 = gBh0 + 16 * DD;
    const bf16_t* gBl0 = Bl + boff;  const bf16_t* gBl1 = gBl0 + 16 * DD;

    bf16_t* lAh0 = sAh + (w * 2 + 0) * 512;  bf16_t* lAh1 = sAh + (w * 2 + 1) * 512;
    bf16_t* lAl0 = sAl + (w * 2 + 0) * 512;  bf16_t* lAl1 = sAl + (w * 2 + 1) * 512;
    bf16_t* lBh0 = sBh + (w * 2 + 0) * 512;  bf16_t* lBh1 = sBh + (w * 2 + 1) * 512;
    bf16_t* lBl0 = sBl + (w * 2 + 0) * 512;  bf16_t* lBl1 = sBl + (w * 2 + 1) * 512;

    for (int kt = 0; kt < DD / 32; ++kt) {
        const int k0 = kt * 32;
        async_copy16(gAh0 + k0, lAh0);
        async_copy16(gAh1 + k0, lAh1);
        async_copy16(gAl0 + k0, lAl0);
        async_copy16(gAl1 + k0, lAl1);
        async_copy16(gBh0 + k0, lBh0);
        async_copy16(gBh1 + k0, lBh1);
        async_copy16(gBl0 + k0, lBl0);
        async_copy16(gBl1 + k0, lBl1);
        __syncthreads();

        bf16x8 ah[4], al[4], bh[4], bl[4];
#pragma unroll
        for (int i = 0; i < 4; ++i) {
            const int ra = (qr + 16 * i + r16) * 32 + q * 8;
            ah[i] = *(const bf16x8*)(sAh + ra);
            al[i] = *(const bf16x8*)(sAl + ra);
        }
#pragma unroll
        for (int j = 0; j < 4; ++j) {
            const int rb = (qc + 16 * j + r16) * 32 + q * 8;
            bh[j] = *(const bf16x8*)(sBh + rb);
            bl[j] = *(const bf16x8*)(sBl + rb);
        }
#pragma unroll
        for (int i = 0; i < 4; ++i)
#pragma unroll
            for (int j = 0; j < 4; ++j) {
                acc[i][j] = __builtin_amdgcn_mfma_f32_16x16x32_bf16(
                    al[i], bh[j], acc[i][j], 0, 0, 0);
                acc[i][j] = __builtin_amdgcn_mfma_f32_16x16x32_bf16(
                    ah[i], bl[j], acc[i][j], 0, 0, 0);
                acc[i][j] = __builtin_amdgcn_mfma_f32_16x16x32_bf16(
                    ah[i], bh[j], acc[i][j], 0, 0, 0);
            }
        __syncthreads();
    }

    // C/D layout: col = lane&15, row = (lane>>4)*4 + reg  (m89-verified)
#pragma unroll
    for (int i = 0; i < 4; ++i)
#pragma unroll
        for (int j = 0; j < 4; ++j) {
            const int col = bn * 128 + qc + 16 * j + r16;
#pragma unroll
            for (int r = 0; r < 4; ++r) {
                const int row = bm * 128 + qr + 16 * i + q * 4 + r;
                C[(long)row * NN + col] = acc[i][j][r];
            }
        }
}

// ---------------------------------------------------------------------------
// probs[b,k,o]: masked -> uniform 1/6 (all -1e18 logits), else softmax over O.
__global__ __launch_bounds__(256) void probs_kernel(
    const float* __restrict__ g, const int* __restrict__ mask,
    float* __restrict__ probs)
{
    const int bk = blockIdx.x * 256 + threadIdx.x;
    if (bk >= BB * KK) return;
    if (mask[bk] != 0) {
        const float u = 1.0f / 6.0f;
#pragma unroll
        for (int o = 0; o < OO; ++o) probs[bk * OO + o] = u;
    } else {
        float p[OO];
        float m = -1e30f;
#pragma unroll
        for (int o = 0; o < OO; ++o) m = fmaxf(m, g[bk * OO + o]);
        float ssum = 0.f;
#pragma unroll
        for (int o = 0; o < OO; ++o) { p[o] = expf(g[bk * OO + o] - m); ssum += p[o]; }
        const float inv = 1.0f / ssum;
#pragma unroll
        for (int o = 0; o < OO; ++o) probs[bk * OO + o] = p[o] * inv;
    }
}

// ---------------------------------------------------------------------------
// s[b,o,e] = sum_k probs[b,k,o] * priors[b,k,o,e]; k split 8-way + atomicAdd.
__global__ __launch_bounds__(256) void s_kernel(
    const float* __restrict__ priors, const float* __restrict__ probs,
    float* __restrict__ s)
{
    const int bo = blockIdx.x;            // 0..47 = b*6+o
    const int b = bo / OO, o = bo % OO;
    const int kbase = blockIdx.y * 128;
    const int t = threadIdx.x;
    const int e = t & 127;
    const int kh = t >> 7;
    float accv = 0.f;
    const int k0 = kbase + kh * 64;
    for (int kk = 0; kk < 64; ++kk) {
        const long row = (long)(b * KK + k0 + kk) * OO + o;
        accv = fmaf(probs[row], priors[row * EE + e], accv);
    }
    __shared__ float red[256];
    red[t] = accv;
    __syncthreads();
    if (t < 128)
        atomicAdd(&s[b * NN + o * EE + e], red[t] + red[t + 128]);
}

// ---------------------------------------------------------------------------
__global__ __launch_bounds__(128) void squash_kernel(
    const float* __restrict__ s, float* __restrict__ v)
{
    const int bo = blockIdx.x;        // 0..47
    const int e = threadIdx.x;        // 0..127
    const float x = s[bo * EE + e];
    float sq = x * x;
#pragma unroll
    for (int off = 32; off > 0; off >>= 1) sq += __shfl_down(sq, off, 64);
    __shared__ float wsum[2];
    if ((threadIdx.x & 63) == 0) wsum[threadIdx.x >> 6] = sq;
    __syncthreads();
    const float total = wsum[0] + wsum[1];
    v[bo * EE + e] = total / (1.0f + total) * x / (sqrtf(total) + 1e-8f);
}

// ---------------------------------------------------------------------------
// g[b,k,o] += dot(priors[b,k,o,:], v[b,o,:]); one wave per (b,k,o) row.
__global__ __launch_bounds__(256) void gupd_kernel(
    const float* __restrict__ priors, const float* __restrict__ v,
    float* __restrict__ g)
{
    const int wid = blockIdx.x * 4 + (threadIdx.x >> 6);
    const int lane = threadIdx.x & 63;
    const int b = wid / (KK * OO);
    const int o = wid % OO;
    const float* pr = priors + (long)wid * EE;
    const float* vb = v + b * NN + o * EE;
    float sum = pr[lane] * vb[lane] + pr[lane + 64] * vb[lane + 64];
#pragma unroll
    for (int off = 32; off > 0; off >>= 1) sum += __shfl_down(sum, off, 64);
    if (lane == 0) g[wid] += sum;
}

// ---------------------------------------------------------------------------
// Broadcast V (B,O,E) and P (B,K,O) over L into f32 output, 4 elems/thread.
__global__ __launch_bounds__(256) void bcast_kernel(
    const float* __restrict__ V, const float* __restrict__ P,
    float* __restrict__ out)
{
    const long base = ((long)blockIdx.x * 256 + threadIdx.x) * 4;
    const long NV = (long)BB * LL * OO * EE;    // 6,291,456
    const float* src;
    if (base < NV) {
        const long b  = base / ((long)LL * OO * EE);   // /786432
        const int off = (int)(base % NN);              // row repeats every 768
        src = V + b * NN + off;
    } else {
        const long b2 = base - NV;
        const long b  = b2 / ((long)LL * KK * OO);     // /6,291,456
        const int off = (int)(b2 % (KK * OO));         // row repeats every 6144
        src = P + b * (KK * OO) + off;
    }
    *(float4*)(out + base) = *(const float4*)(src);
}

// ---------------------------------------------------------------------------
extern "C" void kernel_launch(void* const* d_in, const int* in_sizes, int n_in,
                              void* d_out, int out_size, void* d_ws, size_t ws_size,
                              hipStream_t stream)
{
    (void)in_sizes; (void)n_in; (void)out_size; (void)ws_size;
    const float* u    = (const float*)d_in[0];
    // d_in[1] (context_sequence) is never read by the reference computation.
    const float* W    = (const float*)d_in[2];
    const int*   mask = (const int*)d_in[3];
    float*       out  = (float*)d_out;

    char* ws = (char*)d_ws;
    size_t off = 0;
    float*  priors = (float*)(ws + off);  off += (size_t)8192 * NN * 4;      // 25,165,824
    bf16_t* Ah     = (bf16_t*)(ws + off); off += (size_t)8192 * DD * 2;      // 16,777,216
    bf16_t* Al     = (bf16_t*)(ws + off); off += (size_t)8192 * DD * 2;      // 16,777,216
    bf16_t* Wth    = (bf16_t*)(ws + off); off += (size_t)OO * EE * DD * 2;   //  1,572,864
    bf16_t* Wtl    = (bf16_t*)(ws + off); off += (size_t)OO * EE * DD * 2;   //  1,572,864
    float*  g      = (float*)(ws + off);  off += (size_t)BB * KK * OO * 4;   //    196,608
    float*  probs  = (float*)(ws + off);  off += (size_t)BB * KK * OO * 4;   //    196,608
    float*  s      = (float*)(ws + off);  off += (size_t)BB * NN * 4;        //     24,576
    float*  v      = (float*)(ws + off);                                      //     24,576

    hipLaunchKernelGGL(convert_a, dim3(8192), dim3(256), 0, stream, u, Ah, Al);
    hipLaunchKernelGGL(convert_w, dim3(32, 4, 6), dim3(256), 0, stream, W, Wth, Wtl);
    hipMemsetAsync(g, 0, BB * KK * OO * sizeof(float), stream);
    hipLaunchKernelGGL(gemm_priors, dim3(64, 6), dim3(256), 0, stream,
                       Ah, Al, Wth, Wtl, priors);

    for (int it = 0; it < 3; ++it) {
        hipLaunchKernelGGL(probs_kernel, dim3(32), dim3(256), 0, stream, g, mask, probs);
        hipMemsetAsync(s, 0, BB * NN * sizeof(float), stream);
        hipLaunchKernelGGL(s_kernel, dim3(48, 8), dim3(256), 0, stream, priors, probs, s);
        hipLaunchKernelGGL(squash_kernel, dim3(48), dim3(128), 0, stream, s, v);
        if (it < 2)
            hipLaunchKernelGGL(gupd_kernel, dim3(BB * KK * OO / 4), dim3(256), 0, stream,
                               priors, v, g);
    }
    hipLaunchKernelGGL(bcast_kernel, dim3(55296), dim3(256), 0, stream, v, probs, out);
}

// Round 3
// 372.668 us; speedup vs baseline: 1.0410x; 1.0410x over previous
//
#include <hip/hip_runtime.h>
#include <hip/hip_bf16.h>
#include <stdint.h>

typedef __bf16 bf16_t;
typedef __bf16 bf16x8 __attribute__((ext_vector_type(8)));
typedef float f32x4 __attribute__((ext_vector_type(4)));

#define BB 8
#define KK 1024
#define LL 1024
#define DD 1024
#define OO 6
#define EE 128
#define NN 768   // OO*EE

// ---------------------------------------------------------------------------
__device__ __forceinline__ void async_copy16(const void* gptr, void* lds) {
    __builtin_amdgcn_global_load_lds(
        (__attribute__((address_space(1))) void*)gptr,
        (__attribute__((address_space(3))) void*)lds,
        16, 0, 0);
}

__device__ __forceinline__ void split_bf16(float x, bf16_t& hi, bf16_t& lo) {
    hi = (bf16_t)x;
    lo = (bf16_t)(x - (float)hi);   // residual; lo captures next 8 mantissa bits
}

// ---------------------------------------------------------------------------
// A (8192,1024) f32 -> Ah, Al bf16 planes (row-major, same shape).
__global__ __launch_bounds__(256) void convert_a(
    const float* __restrict__ A, bf16_t* __restrict__ Ah, bf16_t* __restrict__ Al)
{
    const long i = ((long)blockIdx.x * 256 + threadIdx.x) * 4;
    const float4 x = *(const float4*)(A + i);
    union { bf16_t h[4]; uint2 u; } ph, pl;
    split_bf16(x.x, ph.h[0], pl.h[0]);
    split_bf16(x.y, ph.h[1], pl.h[1]);
    split_bf16(x.z, ph.h[2], pl.h[2]);
    split_bf16(x.w, ph.h[3], pl.h[3]);
    *(uint2*)(Ah + i) = ph.u;
    *(uint2*)(Al + i) = pl.u;
}

// ---------------------------------------------------------------------------
// W (O,D,E) f32 -> Wt_hi, Wt_lo (O,E,D) bf16 (transposed: GEMM-B d-contig).
__global__ __launch_bounds__(256) void convert_w(
    const float* __restrict__ W, bf16_t* __restrict__ Wth, bf16_t* __restrict__ Wtl)
{
    __shared__ float t[32][33];
    const int o  = blockIdx.z;
    const int d0 = blockIdx.x * 32;
    const int e0 = blockIdx.y * 32;
    const int tx = threadIdx.x & 31;
    const int ty = threadIdx.x >> 5;   // 0..7
    const float* Wo = W + (long)o * DD * EE;
    bf16_t* Ho = Wth + (long)o * EE * DD;
    bf16_t* Lo = Wtl + (long)o * EE * DD;
#pragma unroll
    for (int p = 0; p < 4; ++p)
        t[p * 8 + ty][tx] = Wo[(long)(d0 + p * 8 + ty) * EE + e0 + tx];
    __syncthreads();
#pragma unroll
    for (int p = 0; p < 4; ++p) {
        const float val = t[tx][p * 8 + ty];
        bf16_t h, l;
        split_bf16(val, h, l);
        const long idx = (long)(e0 + p * 8 + ty) * DD + d0 + tx;
        Ho[idx] = h;
        Lo[idx] = l;
    }
}

// ---------------------------------------------------------------------------
// priors GEMM, split precision: C ~= AhBh + AlBh + AhBl, f32 out.
// 128x64 tile, BK=32, grid (64,12) = 768 blocks (3+/CU). 4 waves in 2x2;
// each wave 64x32 via 4x2 mfma 16x16x32.
__global__ __launch_bounds__(256) void gemm_priors(
    const bf16_t* __restrict__ Ah, const bf16_t* __restrict__ Al,
    const bf16_t* __restrict__ Bh, const bf16_t* __restrict__ Bl,
    float* __restrict__ C)
{
    __shared__ alignas(16) bf16_t sAh[128 * 32];
    __shared__ alignas(16) bf16_t sAl[128 * 32];
    __shared__ alignas(16) bf16_t sBh[64 * 32];
    __shared__ alignas(16) bf16_t sBl[64 * 32];

    const int tid  = threadIdx.x;
    const int w    = tid >> 6;
    const int lane = tid & 63;
    const int bm   = blockIdx.x;   // 0..63  (M/128)
    const int bn   = blockIdx.y;   // 0..11  (N/64)
    const int qr   = (w >> 1) * 64;
    const int qc   = (w & 1) * 32;
    const int r16  = lane & 15;
    const int q    = lane >> 4;

    f32x4 acc[4][2] = {};

    // A staging: instr (w,i) covers tile rows w*32+i*16..+15; lane->row lane>>2,
    // k-elems (lane&3)*8. B staging: instr w covers rows w*16..+15.
    const int mrowA = w * 32 + (lane >> 2);
    const int mrowB = w * 16 + (lane >> 2);
    const int kcol  = (lane & 3) * 8;

    const long aoff = (long)(bm * 128 + mrowA) * DD + kcol;
    const long boff = (long)(bn * 64  + mrowB) * DD + kcol;
    const bf16_t* gAh0 = Ah + aoff;  const bf16_t* gAh1 = gAh0 + 16 * DD;
    const bf16_t* gAl0 = Al + aoff;  const bf16_t* gAl1 = gAl0 + 16 * DD;
    const bf16_t* gBh  = Bh + boff;
    const bf16_t* gBl  = Bl + boff;

    bf16_t* lAh0 = sAh + (w * 2 + 0) * 512;
    bf16_t* lAh1 = sAh + (w * 2 + 1) * 512;
    bf16_t* lAl0 = sAl + (w * 2 + 0) * 512;
    bf16_t* lAl1 = sAl + (w * 2 + 1) * 512;
    bf16_t* lBh  = sBh + w * 512;
    bf16_t* lBl  = sBl + w * 512;

    for (int kt = 0; kt < DD / 32; ++kt) {
        const int k0 = kt * 32;
        async_copy16(gAh0 + k0, lAh0);
        async_copy16(gAh1 + k0, lAh1);
        async_copy16(gAl0 + k0, lAl0);
        async_copy16(gAl1 + k0, lAl1);
        async_copy16(gBh  + k0, lBh);
        async_copy16(gBl  + k0, lBl);
        __syncthreads();

        bf16x8 ah[4], al[4], bh[2], bl[2];
#pragma unroll
        for (int i = 0; i < 4; ++i) {
            const int ra = (qr + 16 * i + r16) * 32 + q * 8;
            ah[i] = *(const bf16x8*)(sAh + ra);
            al[i] = *(const bf16x8*)(sAl + ra);
        }
#pragma unroll
        for (int j = 0; j < 2; ++j) {
            const int rb = (qc + 16 * j + r16) * 32 + q * 8;
            bh[j] = *(const bf16x8*)(sBh + rb);
            bl[j] = *(const bf16x8*)(sBl + rb);
        }
#pragma unroll
        for (int i = 0; i < 4; ++i)
#pragma unroll
            for (int j = 0; j < 2; ++j) {
                acc[i][j] = __builtin_amdgcn_mfma_f32_16x16x32_bf16(
                    al[i], bh[j], acc[i][j], 0, 0, 0);
                acc[i][j] = __builtin_amdgcn_mfma_f32_16x16x32_bf16(
                    ah[i], bl[j], acc[i][j], 0, 0, 0);
                acc[i][j] = __builtin_amdgcn_mfma_f32_16x16x32_bf16(
                    ah[i], bh[j], acc[i][j], 0, 0, 0);
            }
        __syncthreads();
    }

    // C/D layout: col = lane&15, row = (lane>>4)*4 + reg (m89-verified)
#pragma unroll
    for (int i = 0; i < 4; ++i)
#pragma unroll
        for (int j = 0; j < 2; ++j) {
            const int col = bn * 64 + qc + 16 * j + r16;
#pragma unroll
            for (int r = 0; r < 4; ++r) {
                const int row = bm * 128 + qr + 16 * i + q * 4 + r;
                C[(long)row * NN + col] = acc[i][j][r];
            }
        }
}

// ---------------------------------------------------------------------------
// s_part[y][b*6+o][e] = sum_{k in chunk y} w * priors[b,k,o,e];
// w = 1/6 (uniform flag, iter0) or probs[b,k,o]. Plain stores, no atomics.
__global__ __launch_bounds__(256) void s_kernel(
    const float* __restrict__ priors, const float* __restrict__ probs,
    float* __restrict__ s_part, int uniform)
{
    const int bo = blockIdx.x;            // 0..47 = b*6+o
    const int b = bo / OO, o = bo % OO;
    const int kbase = blockIdx.y * 128;   // y = 0..7
    const int t = threadIdx.x;
    const int e = t & 127;
    const int kh = t >> 7;
    float accv = 0.f;
    const int k0 = kbase + kh * 64;
    for (int kk = 0; kk < 64; ++kk) {
        const long row = (long)(b * KK + k0 + kk) * OO + o;
        const float wgt = uniform ? (1.0f / 6.0f) : probs[row];
        accv = fmaf(wgt, priors[row * EE + e], accv);
    }
    __shared__ float red[256];
    red[t] = accv;
    __syncthreads();
    if (t < 128)
        s_part[((long)blockIdx.y * 48 + bo) * EE + e] = red[t] + red[t + 128];
}

// ---------------------------------------------------------------------------
// v = squash(sum_y s_part[y]) per (b,o) row of 128.
__global__ __launch_bounds__(128) void squash_kernel(
    const float* __restrict__ s_part, float* __restrict__ v)
{
    const int bo = blockIdx.x;        // 0..47
    const int e = threadIdx.x;        // 0..127
    float x = 0.f;
#pragma unroll
    for (int y = 0; y < 8; ++y) x += s_part[((long)y * 48 + bo) * EE + e];
    float sq = x * x;
#pragma unroll
    for (int off = 32; off > 0; off >>= 1) sq += __shfl_down(sq, off, 64);
    __shared__ float wsum[2];
    if ((threadIdx.x & 63) == 0) wsum[threadIdx.x >> 6] = sq;
    __syncthreads();
    const float total = wsum[0] + wsum[1];
    v[bo * EE + e] = total / (1.0f + total) * x / (sqrtf(total) + 1e-8f);
}

// ---------------------------------------------------------------------------
// Fused logits-update + softmax: one wave per (b,k).
// delta_o = dot(priors[b,k,o,:], v[b,o,:]); g' = (read_g ? g : 0) + delta;
// probs = masked ? 1/6 : softmax(g'); store g' if store_g.
__global__ __launch_bounds__(256) void fused_pg_kernel(
    const float* __restrict__ priors, const float* __restrict__ v,
    const int* __restrict__ mask, float* __restrict__ g,
    float* __restrict__ probs, int read_g, int store_g)
{
    const int wid  = blockIdx.x * 4 + (threadIdx.x >> 6);   // (b,k) = wid
    const int lane = threadIdx.x & 63;
    const int b = wid >> 10;
    const float* pr = priors + (long)wid * NN;
    const float* vb = v + b * NN;

    float po[OO];
#pragma unroll
    for (int o = 0; o < OO; ++o) {
        const int j0 = o * EE + lane;
        po[o] = pr[j0] * vb[j0] + pr[j0 + 64] * vb[j0 + 64];
    }
#pragma unroll
    for (int off = 32; off > 0; off >>= 1)
#pragma unroll
        for (int o = 0; o < OO; ++o) po[o] += __shfl_xor(po[o], off, 64);

    // all lanes now hold the 6 deltas
    if (read_g) {
#pragma unroll
        for (int o = 0; o < OO; ++o) po[o] += g[wid * OO + o];
    }
    if (store_g && lane < OO) g[wid * OO + lane] = po[lane];

    float p;
    if (mask[wid] != 0) {
        p = 1.0f / 6.0f;
    } else {
        float m = po[0];
#pragma unroll
        for (int o = 1; o < OO; ++o) m = fmaxf(m, po[o]);
        float ssum = 0.f;
#pragma unroll
        for (int o = 0; o < OO; ++o) { po[o] = expf(po[o] - m); ssum += po[o]; }
        const float inv = 1.0f / ssum;
        p = ((lane < OO) ? po[lane] : 0.f) * inv;
    }
    if (lane < OO) probs[wid * OO + lane] = p;
}

// ---------------------------------------------------------------------------
// Broadcast V (B,O,E) and P (B,K,O) over L into f32 output, 4 elems/thread.
__global__ __launch_bounds__(256) void bcast_kernel(
    const float* __restrict__ V, const float* __restrict__ P,
    float* __restrict__ out)
{
    const long base = ((long)blockIdx.x * 256 + threadIdx.x) * 4;
    const long NV = (long)BB * LL * OO * EE;    // 6,291,456
    const float* src;
    if (base < NV) {
        const long b  = base / ((long)LL * OO * EE);
        const int off = (int)(base % NN);
        src = V + b * NN + off;
    } else {
        const long b2 = base - NV;
        const long b  = b2 / ((long)LL * KK * OO);
        const int off = (int)(b2 % (KK * OO));
        src = P + b * (KK * OO) + off;
    }
    *(float4*)(out + base) = *(const float4*)(src);
}

// ---------------------------------------------------------------------------
extern "C" void kernel_launch(void* const* d_in, const int* in_sizes, int n_in,
                              void* d_out, int out_size, void* d_ws, size_t ws_size,
                              hipStream_t stream)
{
    (void)in_sizes; (void)n_in; (void)out_size; (void)ws_size;
    const float* u    = (const float*)d_in[0];
    // d_in[1] (context_sequence) is never read by the reference computation.
    const float* W    = (const float*)d_in[2];
    const int*   mask = (const int*)d_in[3];
    float*       out  = (float*)d_out;

    char* ws = (char*)d_ws;
    size_t off = 0;
    float*  priors = (float*)(ws + off);  off += (size_t)8192 * NN * 4;      // 25,165,824
    bf16_t* Ah     = (bf16_t*)(ws + off); off += (size_t)8192 * DD * 2;      // 16,777,216
    bf16_t* Al     = (bf16_t*)(ws + off); off += (size_t)8192 * DD * 2;      // 16,777,216
    bf16_t* Wth    = (bf16_t*)(ws + off); off += (size_t)OO * EE * DD * 2;   //  1,572,864
    bf16_t* Wtl    = (bf16_t*)(ws + off); off += (size_t)OO * EE * DD * 2;   //  1,572,864
    float*  g      = (float*)(ws + off);  off += (size_t)BB * KK * OO * 4;   //    196,608
    float*  probs  = (float*)(ws + off);  off += (size_t)BB * KK * OO * 4;   //    196,608
    float*  s_part = (float*)(ws + off);  off += (size_t)8 * 48 * EE * 4;    //    196,608
    float*  v      = (float*)(ws + off);                                      //     24,576

    hipLaunchKernelGGL(convert_a, dim3(8192), dim3(256), 0, stream, u, Ah, Al);
    hipLaunchKernelGGL(convert_w, dim3(32, 4, 6), dim3(256), 0, stream, W, Wth, Wtl);
    hipLaunchKernelGGL(gemm_priors, dim3(64, 12), dim3(256), 0, stream,
                       Ah, Al, Wth, Wtl, priors);

    // iter 0: probs is exactly uniform 1/6 (softmax of all-zero or all-NEG_INF)
    hipLaunchKernelGGL(s_kernel, dim3(48, 8), dim3(256), 0, stream,
                       priors, (const float*)nullptr, s_part, 1);
    hipLaunchKernelGGL(squash_kernel, dim3(48), dim3(128), 0, stream, s_part, v);

    // iter 1: g = priors.v0; probs = softmax/uniform
    hipLaunchKernelGGL(fused_pg_kernel, dim3(2048), dim3(256), 0, stream,
                       priors, v, mask, g, probs, 0, 1);
    hipLaunchKernelGGL(s_kernel, dim3(48, 8), dim3(256), 0, stream,
                       priors, probs, s_part, 0);
    hipLaunchKernelGGL(squash_kernel, dim3(48), dim3(128), 0, stream, s_part, v);

    // iter 2: probs = softmax(g + priors.v1) — final probs
    hipLaunchKernelGGL(fused_pg_kernel, dim3(2048), dim3(256), 0, stream,
                       priors, v, mask, g, probs, 1, 0);
    hipLaunchKernelGGL(s_kernel, dim3(48, 8), dim3(256), 0, stream,
                       priors, probs, s_part, 0);
    hipLaunchKernelGGL(squash_kernel, dim3(48), dim3(128), 0, stream, s_part, v);

    hipLaunchKernelGGL(bcast_kernel, dim3(55296), dim3(256), 0, stream, v, probs, out);
}